// Round 1
// baseline (291.384 us; speedup 1.0000x reference)
//
#include <hip/hip_runtime.h>
#include <hip/hip_bf16.h>
#include <math.h>

#define NLOOP 8
#define BB 8
#define LLEN 2048
#define DD 768
#define VV 50288
#define HALT 50277
#define EPSF 1e-5f

#define BN 64
#define BKK 32
#define KSTEPS (DD / BKK)              // 24
#define NBLK ((VV + BN - 1) / BN)      // 786

typedef short bf16x8 __attribute__((ext_vector_type(8)));
typedef float f32x4 __attribute__((ext_vector_type(4)));

__device__ __forceinline__ unsigned short f32_to_bf16(float f) {
    unsigned u = __builtin_bit_cast(unsigned, f);
    unsigned r = (u + 0x7FFFu + ((u >> 16) & 1u)) >> 16;
    return (unsigned short)r;
}

// ---------------- Kernel 1: gather + RMSNorm + target logits ----------------
__global__ __launch_bounds__(256) void k_prep(
    const float* __restrict__ x, const float* __restrict__ res,
    const float* __restrict__ nw, const float* __restrict__ W,
    const int* __restrict__ ans_starts, const int* __restrict__ chain_targets,
    const int* __restrict__ chain_lens,
    unsigned short* __restrict__ hbf, float* __restrict__ tgt_logit)
{
    int lb = blockIdx.x, l = lb >> 3, b = lb & 7;
    int tid = threadIdx.x, lane = tid & 63, wave = tid >> 6;
    int as = ans_starts[b];
    int pos = as - 1;
    pos = pos < 0 ? 0 : (pos > LLEN - 1 ? LLEN - 1 : pos);
    size_t base = ((size_t)lb * LLEN + (size_t)pos) * DD;

    float hv[3];
    float ss = 0.f;
#pragma unroll
    for (int i = 0; i < 3; ++i) {
        int d = tid + i * 256;
        float v = x[base + d] + res[base + d];
        hv[i] = v;
        ss += v * v;
    }
#pragma unroll
    for (int off = 32; off; off >>= 1) ss += __shfl_down(ss, off);
    __shared__ float red[4];
    __shared__ float bc;
    if (lane == 0) red[wave] = ss;
    __syncthreads();
    if (tid == 0) bc = red[0] + red[1] + red[2] + red[3];
    __syncthreads();
    float rs = rsqrtf(bc / (float)DD + EPSF);

    int cl = chain_lens[b];
    int tix = l < cl - 1 ? l : cl - 1;
    int tgt = chain_targets[b * NLOOP + tix];
    bool tok = (tgt >= 0) && (tgt < VV);

    float dp = 0.f;
#pragma unroll
    for (int i = 0; i < 3; ++i) {
        int d = tid + i * 256;
        float h = hv[i] * rs * nw[d];
        hbf[(size_t)lb * DD + d] = f32_to_bf16(h);
        if (tok) dp += h * W[(size_t)tgt * DD + d];
    }
#pragma unroll
    for (int off = 32; off; off >>= 1) dp += __shfl_down(dp, off);
    __syncthreads();
    if (lane == 0) red[wave] = dp;
    __syncthreads();
    if (tid == 0) tgt_logit[lb] = red[0] + red[1] + red[2] + red[3];
}

// ---------------- Kernel 2: bf16 MFMA logits + fused partial LSE/argmax -----
__global__ __launch_bounds__(256) void k_logits(
    const float* __restrict__ W, const unsigned short* __restrict__ hbf,
    float* __restrict__ pmax, float* __restrict__ psum, int* __restrict__ parg)
{
    __shared__ unsigned short As[2][64 * 32];   // 4 KB each, linear [row][k], source pre-swizzled
    __shared__ unsigned short Bs[2][64 * 56];   // 112B row stride (16B-aligned, 2-way banks)
    __shared__ float wmaxs[4][64];
    __shared__ float wsums[4][64];
    __shared__ int   wargs[4][64];
    __shared__ float bmaxs[64];
    __shared__ int   bargs[64];

    int blk = blockIdx.x;
    int v0 = blk * BN;
    int tid = threadIdx.x;
    int wave = tid >> 6, lane = tid & 63, q = lane >> 4, c = lane & 15;

    // A staging: thread tid writes LDS bytes [tid*16, tid*16+16) = row tid>>2, slot tid&3.
    // Pre-swizzle the global source so LDS slot s of row holds k-chunk s ^ ((row>>1)&3).
    int rowa = tid >> 2, sa = tid & 3;
    int kchA = sa ^ ((rowa >> 1) & 3);
    const unsigned short* gA = hbf + (size_t)rowa * DD + kchA * 8;

    // B staging: thread loads rows r1, r1+32; 4 consecutive f32 at koff
    int r1 = tid >> 3, koff = (tid & 7) * 4;
    int vB0 = v0 + r1, vB1 = v0 + r1 + 32;
    bool okB0 = vB0 < VV, okB1 = vB1 < VV;
    const float* gB0 = W + (size_t)vB0 * DD + koff;
    const float* gB1 = W + (size_t)vB1 * DD + koff;

    float4 rb0 = make_float4(0.f, 0.f, 0.f, 0.f), rb1 = rb0;

    auto stage = [&](int k0, int bufi) {
        __builtin_amdgcn_global_load_lds(
            (const __attribute__((address_space(1))) unsigned int*)(gA + k0),
            (__attribute__((address_space(3))) unsigned int*)(&As[bufi][wave * 512]),
            16, 0, 0);
        rb0 = okB0 ? *(const float4*)(gB0 + k0) : make_float4(0.f, 0.f, 0.f, 0.f);
        rb1 = okB1 ? *(const float4*)(gB1 + k0) : make_float4(0.f, 0.f, 0.f, 0.f);
    };

    f32x4 acc[4];
#pragma unroll
    for (int m = 0; m < 4; ++m) acc[m] = (f32x4){0.f, 0.f, 0.f, 0.f};

    int slot = q ^ ((c >> 1) & 3);   // A read slot (m-independent)

    stage(0, 0);
    int buf = 0;
    for (int ks = 0; ks < KSTEPS; ++ks) {
        asm volatile("s_waitcnt vmcnt(0)" ::: "memory");
        // write B regs (tile ks) into Bs[buf]
        {
            ushort4 w0, w1;
            w0.x = f32_to_bf16(rb0.x); w0.y = f32_to_bf16(rb0.y);
            w0.z = f32_to_bf16(rb0.z); w0.w = f32_to_bf16(rb0.w);
            w1.x = f32_to_bf16(rb1.x); w1.y = f32_to_bf16(rb1.y);
            w1.z = f32_to_bf16(rb1.z); w1.w = f32_to_bf16(rb1.w);
            *(ushort4*)&Bs[buf][r1 * 56 + koff] = w0;
            *(ushort4*)&Bs[buf][(r1 + 32) * 56 + koff] = w1;
        }
        __syncthreads();
        if (ks + 1 < KSTEPS) stage((ks + 1) * BKK, buf ^ 1);

        bf16x8 bfrag = *(const bf16x8*)&Bs[buf][(wave * 16 + c) * 56 + q * 8];
        bf16x8 a0 = *(const bf16x8*)&As[buf][(c + 0)  * 32 + slot * 8];
        bf16x8 a1 = *(const bf16x8*)&As[buf][(c + 16) * 32 + slot * 8];
        bf16x8 a2 = *(const bf16x8*)&As[buf][(c + 32) * 32 + slot * 8];
        bf16x8 a3 = *(const bf16x8*)&As[buf][(c + 48) * 32 + slot * 8];
        acc[0] = __builtin_amdgcn_mfma_f32_16x16x32_bf16(a0, bfrag, acc[0], 0, 0, 0);
        acc[1] = __builtin_amdgcn_mfma_f32_16x16x32_bf16(a1, bfrag, acc[1], 0, 0, 0);
        acc[2] = __builtin_amdgcn_mfma_f32_16x16x32_bf16(a2, bfrag, acc[2], 0, 0, 0);
        acc[3] = __builtin_amdgcn_mfma_f32_16x16x32_bf16(a3, bfrag, acc[3], 0, 0, 0);
        buf ^= 1;
    }

    // ---- fused block-level max / argmax / sumexp over this block's 64 cols ----
    int colg = v0 + wave * 16 + c;
    bool cval = colg < VV;
    const float NEGINF = -__builtin_inff();

#pragma unroll
    for (int m = 0; m < 4; ++m) {
#pragma unroll
        for (int r = 0; r < 4; ++r) {
            float val = cval ? acc[m][r] : NEGINF;
            int idx = colg;
#pragma unroll
            for (int off = 1; off < 16; off <<= 1) {
                float ov = __shfl_xor(val, off);
                int oi = __shfl_xor(idx, off);
                if (ov > val || (ov == val && oi < idx)) { val = ov; idx = oi; }
            }
            if (c == 0) {
                int row = 16 * m + 4 * q + r;
                wmaxs[wave][row] = val;
                wargs[wave][row] = idx;
            }
        }
    }
    __syncthreads();
    if (tid < 64) {
        float M = NEGINF; int A_ = 0x7fffffff;
#pragma unroll
        for (int w = 0; w < 4; ++w) {
            float v = wmaxs[w][tid];
            if (v > M) { M = v; A_ = wargs[w][tid]; }
        }
        bmaxs[tid] = M; bargs[tid] = A_;
    }
    __syncthreads();
#pragma unroll
    for (int m = 0; m < 4; ++m) {
#pragma unroll
        for (int r = 0; r < 4; ++r) {
            int row = 16 * m + 4 * q + r;
            float M = bmaxs[row];
            float e = cval ? __expf(acc[m][r] - M) : 0.f;
#pragma unroll
            for (int off = 1; off < 16; off <<= 1) e += __shfl_xor(e, off);
            if (c == 0) wsums[wave][row] = e;
        }
    }
    __syncthreads();
    if (tid < 64) {
        float s = wsums[0][tid] + wsums[1][tid] + wsums[2][tid] + wsums[3][tid];
        pmax[(size_t)blk * 64 + tid] = bmaxs[tid];
        psum[(size_t)blk * 64 + tid] = s;
        parg[(size_t)blk * 64 + tid] = bargs[tid];
    }
}

// ---------------- Kernel 3: combine partials + scalar epilogue --------------
__global__ __launch_bounds__(64) void k_final(
    const float* __restrict__ pmax, const float* __restrict__ psum,
    const int* __restrict__ parg, const float* __restrict__ tgt_logit,
    const int* __restrict__ ans_starts, const int* __restrict__ chain_targets,
    const int* __restrict__ chain_lens, float* __restrict__ out)
{
    __shared__ float logZ[64];
    __shared__ int pred[64];
    int r = threadIdx.x;
    {
        // pass 1: global max + first-occurrence argmax (blocks ascend in v)
        float M = -__builtin_inff(); int arg = 0;
        for (int i = 0; i < NBLK; ++i) {
            float m = pmax[(size_t)i * 64 + r];
            if (m > M) { M = m; arg = parg[(size_t)i * 64 + r]; }
        }
        // pass 2: independent-term sum of exp
        float S = 0.f;
        for (int i = 0; i < NBLK; ++i) {
            S += psum[(size_t)i * 64 + r] * __expf(pmax[(size_t)i * 64 + r] - M);
        }
        logZ[r] = M + logf(S);
        pred[r] = arg;
    }
    __syncthreads();
    if (r == 0) {
        float loop_loss[NLOOP], loop_acc[NLOOP], hasf[NLOOP];
        float n_has = 0.f, hms = 0.f, hcs = 0.f;
        for (int l = 0; l < NLOOP; ++l) {
            float cnt = 0.f, se = 0.f, sc = 0.f;
            for (int b = 0; b < BB; ++b) {
                int cl = chain_lens[b];
                int ti = l < cl - 1 ? l : cl - 1;
                int tgt = chain_targets[b * NLOOP + ti];
                int as = ans_starts[b];
                bool valid = (as >= 1) && (as < LLEN) && (tgt < VV);
                int idx = l * BB + b;
                float ce = logZ[idx] - tgt_logit[idx];
                float corr = (pred[idx] == tgt) ? 1.f : 0.f;
                if (valid) {
                    cnt += 1.f; se += ce; sc += corr;
                    if (tgt == HALT) { hms += 1.f; hcs += corr; }
                }
            }
            bool has = cnt > 0.f;
            hasf[l] = has ? 1.f : 0.f;
            n_has += hasf[l];
            float denom = cnt > 1.f ? cnt : 1.f;
            loop_loss[l] = has ? se / denom : 0.f;
            loop_acc[l]  = has ? sc / denom : 0.f;
        }
        float nn = n_has > 1.f ? n_has : 1.f;
        float avg_loss = 0.f, avg_acc = 0.f;
        for (int l = 0; l < NLOOP; ++l) {
            avg_loss += loop_loss[l] * hasf[l];
            avg_acc  += loop_acc[l]  * hasf[l];
        }
        avg_loss /= nn; avg_acc /= nn;
        int last_valid = NLOOP - 1;   // matches jnp.argmax on all-false reversed
        for (int l = NLOOP - 1; l >= 0; --l) if (hasf[l] > 0.f) { last_valid = l; break; }
        float ams = 0.f, aacc = 0.f;
        for (int l = 0; l < NLOOP; ++l) {
            float mask = (n_has > 1.f) ? (hasf[l] * ((l != last_valid) ? 1.f : 0.f)) : hasf[l];
            ams += mask; aacc += loop_acc[l] * mask;
        }
        float answer_acc = (ams > 0.f) ? (aacc / (ams > 1.f ? ams : 1.f)) : avg_acc;
        float halt_acc = (hms > 0.f) ? (hcs / (hms > 1.f ? hms : 1.f)) : 0.f;
        out[0] = avg_loss; out[1] = avg_acc; out[2] = answer_acc; out[3] = halt_acc;
    }
}

extern "C" void kernel_launch(void* const* d_in, const int* in_sizes, int n_in,
                              void* d_out, int out_size, void* d_ws, size_t ws_size,
                              hipStream_t stream) {
    const float* x   = (const float*)d_in[0];
    const float* res = (const float*)d_in[1];
    const float* nw  = (const float*)d_in[2];
    const float* W   = (const float*)d_in[3];
    const int* ans   = (const int*)d_in[4];
    const int* ct    = (const int*)d_in[5];
    const int* cl    = (const int*)d_in[6];
    float* out = (float*)d_out;

    char* ws = (char*)d_ws;
    unsigned short* hbf = (unsigned short*)ws;                       // 64*768*2 = 98304 B
    float* tgtl = (float*)(ws + 98304);                              // 256 B
    float* pmax = (float*)(ws + 98560);                              // 64*NBLK*4
    float* psum = (float*)(ws + 98560 + (size_t)64 * NBLK * 4);
    int*   parg = (int*)  (ws + 98560 + (size_t)2 * 64 * NBLK * 4);

    k_prep<<<64, 256, 0, stream>>>(x, res, nw, W, ans, ct, cl, hbf, tgtl);
    k_logits<<<NBLK, 256, 0, stream>>>(W, hbf, pmax, psum, parg);
    k_final<<<1, 64, 0, stream>>>(pmax, psum, parg, tgtl, ans, ct, cl, out);
}

// Round 2
// 58.297 us; speedup vs baseline: 4.9983x; 4.9983x over previous
//
#include <hip/hip_runtime.h>
#include <hip/hip_bf16.h>
#include <math.h>

#define NLOOP 8
#define BB 8
#define LLEN 2048
#define DD 768
#define VV 50288
#define HALT 50277
#define EPSF 1e-5f

#define BN 64
#define BKK 32
#define KSTEPS (DD / BKK)              // 24
#define NBLK ((VV + BN - 1) / BN)      // 786

typedef short bf16x8 __attribute__((ext_vector_type(8)));
typedef float f32x4 __attribute__((ext_vector_type(4)));

__device__ __forceinline__ unsigned short f32_to_bf16(float f) {
    unsigned u = __builtin_bit_cast(unsigned, f);
    unsigned r = (u + 0x7FFFu + ((u >> 16) & 1u)) >> 16;
    return (unsigned short)r;
}

// ---------------- Kernel 1: gather + RMSNorm + target logits ----------------
__global__ __launch_bounds__(256) void k_prep(
    const float* __restrict__ x, const float* __restrict__ res,
    const float* __restrict__ nw, const float* __restrict__ W,
    const int* __restrict__ ans_starts, const int* __restrict__ chain_targets,
    const int* __restrict__ chain_lens,
    unsigned short* __restrict__ hbf, float* __restrict__ tgt_logit)
{
    int lb = blockIdx.x, l = lb >> 3, b = lb & 7;
    int tid = threadIdx.x, lane = tid & 63, wave = tid >> 6;
    int as = ans_starts[b];
    int pos = as - 1;
    pos = pos < 0 ? 0 : (pos > LLEN - 1 ? LLEN - 1 : pos);
    size_t base = ((size_t)lb * LLEN + (size_t)pos) * DD;

    float hv[3];
    float ss = 0.f;
#pragma unroll
    for (int i = 0; i < 3; ++i) {
        int d = tid + i * 256;
        float v = x[base + d] + res[base + d];
        hv[i] = v;
        ss += v * v;
    }
#pragma unroll
    for (int off = 32; off; off >>= 1) ss += __shfl_down(ss, off);
    __shared__ float red[4];
    __shared__ float bc;
    if (lane == 0) red[wave] = ss;
    __syncthreads();
    if (tid == 0) bc = red[0] + red[1] + red[2] + red[3];
    __syncthreads();
    float rs = rsqrtf(bc / (float)DD + EPSF);

    int cl = chain_lens[b];
    int tix = l < cl - 1 ? l : cl - 1;
    int tgt = chain_targets[b * NLOOP + tix];
    bool tok = (tgt >= 0) && (tgt < VV);

    float dp = 0.f;
#pragma unroll
    for (int i = 0; i < 3; ++i) {
        int d = tid + i * 256;
        float h = hv[i] * rs * nw[d];
        hbf[(size_t)lb * DD + d] = f32_to_bf16(h);
        if (tok) dp += h * W[(size_t)tgt * DD + d];
    }
#pragma unroll
    for (int off = 32; off; off >>= 1) dp += __shfl_down(dp, off);
    __syncthreads();
    if (lane == 0) red[wave] = dp;
    __syncthreads();
    if (tid == 0) tgt_logit[lb] = red[0] + red[1] + red[2] + red[3];
}

// ---------------- Kernel 2: bf16 MFMA logits + fused partial LSE/argmax -----
// Partials written TRANSPOSED: pmax[row * NBLK + blk] for coalesced combine.
__global__ __launch_bounds__(256) void k_logits(
    const float* __restrict__ W, const unsigned short* __restrict__ hbf,
    float* __restrict__ pmax, float* __restrict__ psum, int* __restrict__ parg)
{
    __shared__ unsigned short As[2][64 * 32];   // 4 KB each, linear [row][k], source pre-swizzled
    __shared__ unsigned short Bs[2][64 * 56];   // 112B row stride (16B-aligned, 2-way banks)
    __shared__ float wmaxs[4][64];
    __shared__ float wsums[4][64];
    __shared__ int   wargs[4][64];
    __shared__ float bmaxs[64];
    __shared__ int   bargs[64];

    int blk = blockIdx.x;
    int v0 = blk * BN;
    int tid = threadIdx.x;
    int wave = tid >> 6, lane = tid & 63, q = lane >> 4, c = lane & 15;

    // A staging: thread tid writes LDS bytes [tid*16, tid*16+16) = row tid>>2, slot tid&3.
    // Pre-swizzle the global source so LDS slot s of row holds k-chunk s ^ ((row>>1)&3).
    int rowa = tid >> 2, sa = tid & 3;
    int kchA = sa ^ ((rowa >> 1) & 3);
    const unsigned short* gA = hbf + (size_t)rowa * DD + kchA * 8;

    // B staging: thread loads rows r1, r1+32; 4 consecutive f32 at koff
    int r1 = tid >> 3, koff = (tid & 7) * 4;
    int vB0 = v0 + r1, vB1 = v0 + r1 + 32;
    bool okB0 = vB0 < VV, okB1 = vB1 < VV;
    const float* gB0 = W + (size_t)vB0 * DD + koff;
    const float* gB1 = W + (size_t)vB1 * DD + koff;

    float4 rb0 = make_float4(0.f, 0.f, 0.f, 0.f), rb1 = rb0;

    auto stage = [&](int k0, int bufi) {
        __builtin_amdgcn_global_load_lds(
            (const __attribute__((address_space(1))) unsigned int*)(gA + k0),
            (__attribute__((address_space(3))) unsigned int*)(&As[bufi][wave * 512]),
            16, 0, 0);
        rb0 = okB0 ? *(const float4*)(gB0 + k0) : make_float4(0.f, 0.f, 0.f, 0.f);
        rb1 = okB1 ? *(const float4*)(gB1 + k0) : make_float4(0.f, 0.f, 0.f, 0.f);
    };

    f32x4 acc[4];
#pragma unroll
    for (int m = 0; m < 4; ++m) acc[m] = (f32x4){0.f, 0.f, 0.f, 0.f};

    int slot = q ^ ((c >> 1) & 3);   // A read slot (m-independent)

    stage(0, 0);
    int buf = 0;
    for (int ks = 0; ks < KSTEPS; ++ks) {
        asm volatile("s_waitcnt vmcnt(0)" ::: "memory");
        // write B regs (tile ks) into Bs[buf]
        {
            ushort4 w0, w1;
            w0.x = f32_to_bf16(rb0.x); w0.y = f32_to_bf16(rb0.y);
            w0.z = f32_to_bf16(rb0.z); w0.w = f32_to_bf16(rb0.w);
            w1.x = f32_to_bf16(rb1.x); w1.y = f32_to_bf16(rb1.y);
            w1.z = f32_to_bf16(rb1.z); w1.w = f32_to_bf16(rb1.w);
            *(ushort4*)&Bs[buf][r1 * 56 + koff] = w0;
            *(ushort4*)&Bs[buf][(r1 + 32) * 56 + koff] = w1;
        }
        __syncthreads();
        if (ks + 1 < KSTEPS) stage((ks + 1) * BKK, buf ^ 1);

        bf16x8 bfrag = *(const bf16x8*)&Bs[buf][(wave * 16 + c) * 56 + q * 8];
        bf16x8 a0 = *(const bf16x8*)&As[buf][(c + 0)  * 32 + slot * 8];
        bf16x8 a1 = *(const bf16x8*)&As[buf][(c + 16) * 32 + slot * 8];
        bf16x8 a2 = *(const bf16x8*)&As[buf][(c + 32) * 32 + slot * 8];
        bf16x8 a3 = *(const bf16x8*)&As[buf][(c + 48) * 32 + slot * 8];
        acc[0] = __builtin_amdgcn_mfma_f32_16x16x32_bf16(a0, bfrag, acc[0], 0, 0, 0);
        acc[1] = __builtin_amdgcn_mfma_f32_16x16x32_bf16(a1, bfrag, acc[1], 0, 0, 0);
        acc[2] = __builtin_amdgcn_mfma_f32_16x16x32_bf16(a2, bfrag, acc[2], 0, 0, 0);
        acc[3] = __builtin_amdgcn_mfma_f32_16x16x32_bf16(a3, bfrag, acc[3], 0, 0, 0);
        buf ^= 1;
    }

    // ---- fused block-level max / argmax / sumexp over this block's 64 cols ----
    int colg = v0 + wave * 16 + c;
    bool cval = colg < VV;
    const float NEGINF = -__builtin_inff();

#pragma unroll
    for (int m = 0; m < 4; ++m) {
#pragma unroll
        for (int r = 0; r < 4; ++r) {
            float val = cval ? acc[m][r] : NEGINF;
            int idx = colg;
#pragma unroll
            for (int off = 1; off < 16; off <<= 1) {
                float ov = __shfl_xor(val, off);
                int oi = __shfl_xor(idx, off);
                if (ov > val || (ov == val && oi < idx)) { val = ov; idx = oi; }
            }
            if (c == 0) {
                int row = 16 * m + 4 * q + r;
                wmaxs[wave][row] = val;
                wargs[wave][row] = idx;
            }
        }
    }
    __syncthreads();
    if (tid < 64) {
        float M = NEGINF; int A_ = 0x7fffffff;
#pragma unroll
        for (int w = 0; w < 4; ++w) {
            float v = wmaxs[w][tid];
            if (v > M) { M = v; A_ = wargs[w][tid]; }
        }
        bmaxs[tid] = M; bargs[tid] = A_;
    }
    __syncthreads();
#pragma unroll
    for (int m = 0; m < 4; ++m) {
#pragma unroll
        for (int r = 0; r < 4; ++r) {
            int row = 16 * m + 4 * q + r;
            float M = bmaxs[row];
            float e = cval ? __expf(acc[m][r] - M) : 0.f;
#pragma unroll
            for (int off = 1; off < 16; off <<= 1) e += __shfl_xor(e, off);
            if (c == 0) wsums[wave][row] = e;
        }
    }
    __syncthreads();
    if (tid < 64) {
        float s = wsums[0][tid] + wsums[1][tid] + wsums[2][tid] + wsums[3][tid];
        pmax[(size_t)tid * NBLK + blk] = bmaxs[tid];
        psum[(size_t)tid * NBLK + blk] = s;
        parg[(size_t)tid * NBLK + blk] = bargs[tid];
    }
}

// ---------------- Kernel 3: parallel combine (one block per row) ------------
__global__ __launch_bounds__(256) void k_combine(
    const float* __restrict__ pmax, const float* __restrict__ psum,
    const int* __restrict__ parg, float* __restrict__ logZ, int* __restrict__ pred)
{
    int r = blockIdx.x;                 // row 0..63
    int tid = threadIdx.x;
    int wave = tid >> 6, lane = tid & 63;
    const float NEGINF = -__builtin_inff();

    const float* pm = pmax + (size_t)r * NBLK;
    const float* ps = psum + (size_t)r * NBLK;
    const int*   pa = parg + (size_t)r * NBLK;

    float M = NEGINF; int A_ = 0x7fffffff;
    for (int i = tid; i < NBLK; i += 256) {
        float m = pm[i];
        int a = pa[i];
        if (m > M || (m == M && a < A_)) { M = m; A_ = a; }
    }
#pragma unroll
    for (int off = 1; off < 64; off <<= 1) {
        float ov = __shfl_xor(M, off);
        int oa = __shfl_xor(A_, off);
        if (ov > M || (ov == M && oa < A_)) { M = ov; A_ = oa; }
    }
    __shared__ float sm[4]; __shared__ int sa[4]; __shared__ float ssum[4];
    if (lane == 0) { sm[wave] = M; sa[wave] = A_; }
    __syncthreads();
    if (tid == 0) {
#pragma unroll
        for (int w = 1; w < 4; ++w)
            if (sm[w] > sm[0] || (sm[w] == sm[0] && sa[w] < sa[0])) { sm[0] = sm[w]; sa[0] = sa[w]; }
    }
    __syncthreads();
    float Mg = sm[0];

    float S = 0.f;
    for (int i = tid; i < NBLK; i += 256)
        S += ps[i] * __expf(pm[i] - Mg);
#pragma unroll
    for (int off = 1; off < 64; off <<= 1) S += __shfl_xor(S, off);
    if (lane == 0) ssum[wave] = S;
    __syncthreads();
    if (tid == 0) {
        logZ[r] = Mg + logf(ssum[0] + ssum[1] + ssum[2] + ssum[3]);
        pred[r] = sa[0];
    }
}

// ---------------- Kernel 4: scalar epilogue ---------------------------------
__global__ __launch_bounds__(64) void k_epilogue(
    const float* __restrict__ logZg, const int* __restrict__ predg,
    const float* __restrict__ tgt_logit,
    const int* __restrict__ ans_starts, const int* __restrict__ chain_targets,
    const int* __restrict__ chain_lens, float* __restrict__ out)
{
    __shared__ float logZ[64];
    __shared__ int pred[64];
    int r = threadIdx.x;
    logZ[r] = logZg[r];
    pred[r] = predg[r];
    __syncthreads();
    if (r == 0) {
        float loop_loss[NLOOP], loop_acc[NLOOP], hasf[NLOOP];
        float n_has = 0.f, hms = 0.f, hcs = 0.f;
        for (int l = 0; l < NLOOP; ++l) {
            float cnt = 0.f, se = 0.f, sc = 0.f;
            for (int b = 0; b < BB; ++b) {
                int cl = chain_lens[b];
                int ti = l < cl - 1 ? l : cl - 1;
                int tgt = chain_targets[b * NLOOP + ti];
                int as = ans_starts[b];
                bool valid = (as >= 1) && (as < LLEN) && (tgt < VV);
                int idx = l * BB + b;
                float ce = logZ[idx] - tgt_logit[idx];
                float corr = (pred[idx] == tgt) ? 1.f : 0.f;
                if (valid) {
                    cnt += 1.f; se += ce; sc += corr;
                    if (tgt == HALT) { hms += 1.f; hcs += corr; }
                }
            }
            bool has = cnt > 0.f;
            hasf[l] = has ? 1.f : 0.f;
            n_has += hasf[l];
            float denom = cnt > 1.f ? cnt : 1.f;
            loop_loss[l] = has ? se / denom : 0.f;
            loop_acc[l]  = has ? sc / denom : 0.f;
        }
        float nn = n_has > 1.f ? n_has : 1.f;
        float avg_loss = 0.f, avg_acc = 0.f;
        for (int l = 0; l < NLOOP; ++l) {
            avg_loss += loop_loss[l] * hasf[l];
            avg_acc  += loop_acc[l]  * hasf[l];
        }
        avg_loss /= nn; avg_acc /= nn;
        int last_valid = NLOOP - 1;   // matches jnp.argmax on all-false reversed
        for (int l = NLOOP - 1; l >= 0; --l) if (hasf[l] > 0.f) { last_valid = l; break; }
        float ams = 0.f, aacc = 0.f;
        for (int l = 0; l < NLOOP; ++l) {
            float mask = (n_has > 1.f) ? (hasf[l] * ((l != last_valid) ? 1.f : 0.f)) : hasf[l];
            ams += mask; aacc += loop_acc[l] * mask;
        }
        float answer_acc = (ams > 0.f) ? (aacc / (ams > 1.f ? ams : 1.f)) : avg_acc;
        float halt_acc = (hms > 0.f) ? (hcs / (hms > 1.f ? hms : 1.f)) : 0.f;
        out[0] = avg_loss; out[1] = avg_acc; out[2] = answer_acc; out[3] = halt_acc;
    }
}

extern "C" void kernel_launch(void* const* d_in, const int* in_sizes, int n_in,
                              void* d_out, int out_size, void* d_ws, size_t ws_size,
                              hipStream_t stream) {
    const float* x   = (const float*)d_in[0];
    const float* res = (const float*)d_in[1];
    const float* nw  = (const float*)d_in[2];
    const float* W   = (const float*)d_in[3];
    const int* ans   = (const int*)d_in[4];
    const int* ct    = (const int*)d_in[5];
    const int* cl    = (const int*)d_in[6];
    float* out = (float*)d_out;

    char* ws = (char*)d_ws;
    unsigned short* hbf = (unsigned short*)ws;                       // 64*768*2 = 98304 B
    float* tgtl = (float*)(ws + 98304);                              // 256 B
    size_t off = 98560;
    float* pmax = (float*)(ws + off);  off += (size_t)64 * NBLK * 4; // 201216 B
    float* psum = (float*)(ws + off);  off += (size_t)64 * NBLK * 4;
    int*   parg = (int*)  (ws + off);  off += (size_t)64 * NBLK * 4;
    float* logZ = (float*)(ws + off);  off += 256;
    int*   pred = (int*)  (ws + off);  off += 256;

    k_prep<<<64, 256, 0, stream>>>(x, res, nw, W, ans, ct, cl, hbf, tgtl);
    k_logits<<<NBLK, 256, 0, stream>>>(W, hbf, pmax, psum, parg);
    k_combine<<<64, 256, 0, stream>>>(pmax, psum, parg, logZ, pred);
    k_epilogue<<<1, 64, 0, stream>>>(logZ, pred, tgtl, ans, ct, cl, out);
}